// Round 15
// baseline (159.580 us; speedup 1.0000x reference)
//
#include <hip/hip_runtime.h>

#define BB 2
#define NN 16
#define LQ 512
#define DKk 64
#define DVv 64
#define DDd 128
#define H2 256
#define NEG_INF -1e9f

// ---------------------------------------------------------------------------
// Stage 1 v2 (proven): 2 rows per block, grid 1024, 4 blocks/CU.
// Per-(row,g) fp64 chain unchanged -> bit-identical U/W outputs.
// ---------------------------------------------------------------------------
__global__ __launch_bounds__(256) void mlp_stage1(
    const float* __restrict__ d0, const float* __restrict__ d1,
    const float* __restrict__ W1, const float* __restrict__ b1,
    double* __restrict__ U64, double* __restrict__ W64,
    float* __restrict__ U32, float* __restrict__ W32)
{
    __shared__ float drow[2][DDd];
    int gid = blockIdx.x;            // half(2) x rowgroup(512)
    int half = gid >> 9;
    int r0 = (gid & 511) * 2;        // rows r0..r0+1 of 1024
    const float* din = half ? d1 : d0;
    int w1off = half ? DDd : 0;
    double* o64 = half ? W64 : U64;
    float* o32 = half ? W32 : U32;
    int t = threadIdx.x;
    drow[t >> 7][t & 127] = din[(size_t)(r0 + (t >> 7)) * DDd + (t & 127)];
    __syncthreads();
    int g = t;
    double acc[2] = {};
#pragma unroll 2
    for (int f = 0; f < DDd; f += 4) {
        double w0 = (double)W1[(w1off + f + 0) * H2 + g];
        double w1 = (double)W1[(w1off + f + 1) * H2 + g];
        double w2 = (double)W1[(w1off + f + 2) * H2 + g];
        double w3 = (double)W1[(w1off + f + 3) * H2 + g];
#pragma unroll
        for (int r = 0; r < 2; ++r) {
            float4 dr = *(const float4*)&drow[r][f];
            acc[r] = fma((double)dr.x, w0, acc[r]);
            acc[r] = fma((double)dr.y, w1, acc[r]);
            acc[r] = fma((double)dr.z, w2, acc[r]);
            acc[r] = fma((double)dr.w, w3, acc[r]);
        }
    }
    double bb = half ? 0.0 : (double)b1[g];
#pragma unroll
    for (int r = 0; r < 2; ++r) {
        double a = acc[r] + bb;
        o64[(size_t)(r0 + r) * H2 + g] = a;
        o32[(size_t)(r0 + r) * H2 + g] = (float)a;
    }
}

// ---------------------------------------------------------------------------
// dec_full v8 (kept): 2i x 2j thread tile, g-major LDS, single staging pass;
// in-block fp64 re-eval of |gap|<2e-2 band -> bit-identical decisions.
// ---------------------------------------------------------------------------
__global__ __launch_bounds__(256, 2) void dec_full(
    const float* __restrict__ U32, const float* __restrict__ W32,
    const double* __restrict__ U64, const double* __restrict__ W64,
    const float* __restrict__ W2, const float* __restrict__ b2,
    float* __restrict__ dec_out)
{
    __shared__ __align__(16) float Ut[H2][36];    // [g][i]  36 KB
    __shared__ __align__(16) float Wt[H2][36];    // [g][j]  36 KB
    __shared__ float gvs[H2];
    __shared__ int lbuf[1024];
    __shared__ int lcnt;
    int bid = blockIdx.x;            // b(2) x it(16) x jt(16)
    int b  = bid >> 8;
    int i0 = ((bid >> 4) & 15) * 32;
    int j0 = (bid & 15) * 32;
    int t = threadIdx.x;
    gvs[t] = W2[t * 2 + 1] - W2[t * 2];
    if (t == 0) lcnt = 0;
    float bias = b2[1] - b2[0];
    {   // stage U,W transposed: row = t>>3 (0..31), gq = t&7; 8 f4 each
        int r = t >> 3, gq = t & 7;
        const float* su = U32 + ((size_t)(b * LQ) + i0 + r) * H2;
        const float* sw = W32 + ((size_t)(b * LQ) + j0 + r) * H2;
#pragma unroll
        for (int s = 0; s < 8; ++s) {
            int g = gq * 4 + s * 32;
            float4 u4 = *(const float4*)(su + g);
            Ut[g + 0][r] = u4.x; Ut[g + 1][r] = u4.y;
            Ut[g + 2][r] = u4.z; Ut[g + 3][r] = u4.w;
            float4 w4 = *(const float4*)(sw + g);
            Wt[g + 0][r] = w4.x; Wt[g + 1][r] = w4.y;
            Wt[g + 2][r] = w4.z; Wt[g + 3][r] = w4.w;
        }
    }
    __syncthreads();
    int pi = t >> 4, pj = t & 15;    // i = i0+pi*2+{0,1}; j = j0+pj*2+{0,1}
    float a00 = 0.f, a01 = 0.f, a10 = 0.f, a11 = 0.f;
#pragma unroll 8
    for (int g = 0; g < H2; ++g) {
        float2 u2 = *(const float2*)&Ut[g][pi * 2];
        float2 w2 = *(const float2*)&Wt[g][pj * 2];
        float gv = gvs[g];
        a00 = fmaf(fmaxf(u2.x + w2.x, 0.f), gv, a00);
        a01 = fmaf(fmaxf(u2.x + w2.y, 0.f), gv, a01);
        a10 = fmaf(fmaxf(u2.y + w2.x, 0.f), gv, a10);
        a11 = fmaf(fmaxf(u2.y + w2.y, 0.f), gv, a11);
    }
    int row0 = b * LQ + i0 + pi * 2;
    float g00 = a00 + bias, g01 = a01 + bias;
    float g10 = a10 + bias, g11 = a11 + bias;
    int jb = j0 + pj * 2;
    *(float2*)&dec_out[(size_t)row0 * LQ + jb] =
        make_float2(g00 > 0.f ? 1.f : 0.f, g01 > 0.f ? 1.f : 0.f);
    *(float2*)&dec_out[(size_t)(row0 + 1) * LQ + jb] =
        make_float2(g10 > 0.f ? 1.f : 0.f, g11 > 0.f ? 1.f : 0.f);
    if (fabsf(g00) < 2e-2f) { int lx = atomicAdd(&lcnt, 1); lbuf[lx] = (row0 << 9) | jb; }
    if (fabsf(g01) < 2e-2f) { int lx = atomicAdd(&lcnt, 1); lbuf[lx] = (row0 << 9) | (jb + 1); }
    if (fabsf(g10) < 2e-2f) { int lx = atomicAdd(&lcnt, 1); lbuf[lx] = ((row0 + 1) << 9) | jb; }
    if (fabsf(g11) < 2e-2f) { int lx = atomicAdd(&lcnt, 1); lbuf[lx] = ((row0 + 1) << 9) | (jb + 1); }
    __syncthreads();
    // ---- in-block fp64 re-eval (gap64's exact math/order), wave per pair ----
    int nloc = lcnt;
    int wv = t >> 6, ln = t & 63;
    for (int x = wv; x < nloc; x += 4) {
        int pij = lbuf[x];
        int j = pij & (LQ - 1);
        int prow = pij >> 9;
        int pb = prow >> 9;
        const double* u = U64 + (size_t)prow * H2;
        const double* w = W64 + ((size_t)(pb * LQ) + j) * H2;
        double acc = 0.0;
        for (int g = ln; g < H2; g += 64) {
            double tv = u[g] + w[g];
            tv = tv > 0.0 ? tv : 0.0;
            acc = fma(tv, (double)W2[g * 2 + 1] - (double)W2[g * 2 + 0], acc);
        }
#pragma unroll
        for (int off = 32; off; off >>= 1) acc += __shfl_xor(acc, off, 64);
        if (ln == 0) {
            acc += (double)b2[1] - (double)b2[0];
            dec_out[(size_t)prow * LQ + j] = acc > 0.0 ? 1.f : 0.f;
        }
    }
}

// ---------------------------------------------------------------------------
// Fused attention v9: v8 (QK broadcast + rotated-Pt PV, proven R14 ~49 us)
// + T14 issue-early/use-late on the dec mask: the 16 float4 dec loads are
// issued BEFORE the QK loop (barriers stop the compiler sinking them), so
// their s_waitcnt at softmax finds data long arrived. +64 VGPR is free:
// occupancy is grid-capped at 2 blocks/CU (512 blocks / 256 CU).
// ---------------------------------------------------------------------------
#define QK_R(ar, sa, sb)                                   \
    sa.x = fmaf(ar, b0.x, sa.x); sa.y = fmaf(ar, b0.y, sa.y); \
    sa.z = fmaf(ar, b0.z, sa.z); sa.w = fmaf(ar, b0.w, sa.w); \
    sb.x = fmaf(ar, b1.x, sb.x); sb.y = fmaf(ar, b1.y, sb.y); \
    sb.z = fmaf(ar, b1.z, sb.z); sb.w = fmaf(ar, b1.w, sb.w);

#define SM_ROW(sa, sb, m0, m1, r) {                                             \
    sa.x = m0.x != 0.f ? sa.x * 0.125f : NEG_INF;                               \
    sa.y = m0.y != 0.f ? sa.y * 0.125f : NEG_INF;                               \
    sa.z = m0.z != 0.f ? sa.z * 0.125f : NEG_INF;                               \
    sa.w = m0.w != 0.f ? sa.w * 0.125f : NEG_INF;                               \
    sb.x = m1.x != 0.f ? sb.x * 0.125f : NEG_INF;                               \
    sb.y = m1.y != 0.f ? sb.y * 0.125f : NEG_INF;                               \
    sb.z = m1.z != 0.f ? sb.z * 0.125f : NEG_INF;                               \
    sb.w = m1.w != 0.f ? sb.w * 0.125f : NEG_INF;                               \
    float mx = fmaxf(fmaxf(fmaxf(sa.x, sa.y), fmaxf(sa.z, sa.w)),              \
                     fmaxf(fmaxf(sb.x, sb.y), fmaxf(sb.z, sb.w)));              \
    _Pragma("unroll")                                                            \
    for (int off = 1; off < 64; off <<= 1) mx = fmaxf(mx, __shfl_xor(mx, off, 64)); \
    sa.x = __expf(sa.x - mx); sa.y = __expf(sa.y - mx);                         \
    sa.z = __expf(sa.z - mx); sa.w = __expf(sa.w - mx);                         \
    sb.x = __expf(sb.x - mx); sb.y = __expf(sb.y - mx);                         \
    sb.z = __expf(sb.z - mx); sb.w = __expf(sb.w - mx);                         \
    float sm = sa.x + sa.y + sa.z + sa.w + sb.x + sb.y + sb.z + sb.w;           \
    _Pragma("unroll")                                                            \
    for (int off = 1; off < 64; off <<= 1) sm += __shfl_xor(sm, off, 64);       \
    float inv = 1.f / sm;                                                       \
    sa.x *= inv; sa.y *= inv; sa.z *= inv; sa.w *= inv;                         \
    sb.x *= inv; sb.y *= inv; sb.z *= inv; sb.w *= inv;                         \
    size_t aro = ((size_t)bn * LQ + i0 + ig * 8 + r) * LQ + lane * 4;           \
    *(float4*)&attn[aro] = sa;                                                  \
    *(float4*)&attn[aro + 256] = sb;                                            \
}

// owner-lane Pt write for component cc: rows ig*8..+7 at rotated slot
#define PT_WCC(s0, s1, s2, s3, s4, s5, s6, s7, cc) {                            \
    int jl = L15 * 4 + (cc);                                                    \
    int base = jl * 36 + slot;                                                  \
    *(float4*)&Pt[base]     = make_float4(s0, s1, s2, s3);                      \
    *(float4*)&Pt[base + 4] = make_float4(s4, s5, s6, s7);                      \
}

__global__ __launch_bounds__(256) void fused_attn(
    const float* __restrict__ q, const float* __restrict__ k,
    const float* __restrict__ v, const float* __restrict__ dec,
    float* __restrict__ attn, float* __restrict__ out)
{
    __shared__ __align__(16) float smem[10752];   // 43 KB, phase-overlaid
    float* qT = smem;            // [64 kk][36]      (QK phase)
    float* kT = smem + 2304;     // [16 kk][516]     (QK phase, per chunk)
    float* Pt = smem;            // [64 jl][36]      (PV phase, rotated slots)
    float* Vs = smem + 2304;     // [64 j][68]       (PV phase)
    int bid = blockIdx.x;
    int bn = bid >> 4;
    int i0 = (bid & 15) * 32;
    int b = bn >> 4;
    int t = threadIdx.x;
    int ig = t >> 6;             // wave id: i-rows i0 + ig*8 + (0..7)
    int lane = t & 63;           // QK: j-quads {4*lane, 256+4*lane}

    // ---- T14: issue dec-mask loads EARLY (used only after the QK loop) ----
    float4 md0[8], md1[8];
#pragma unroll
    for (int r = 0; r < 8; ++r) {
        size_t dro = ((size_t)(b * LQ) + i0 + ig * 8 + r) * LQ + lane * 4;
        md0[r] = *(const float4*)&dec[dro];
        md1[r] = *(const float4*)&dec[dro + 256];
    }

    {   // stage qT (transpose): i = t>>3 (0..31), kkq = (t&7)+8*it
        int qi = t >> 3;
        const float* src = q + ((size_t)bn * LQ + i0 + qi) * DKk;
#pragma unroll
        for (int it = 0; it < 2; ++it) {
            int kkq = (t & 7) + it * 8;
            float4 t4 = *(const float4*)(src + kkq * 4);
            qT[(kkq * 4 + 0) * 36 + qi] = t4.x;
            qT[(kkq * 4 + 1) * 36 + qi] = t4.y;
            qT[(kkq * 4 + 2) * 36 + qi] = t4.z;
            qT[(kkq * 4 + 3) * 36 + qi] = t4.w;
        }
    }

    float4 sA0 = {}, sA1 = {}, sA2 = {}, sA3 = {}, sA4 = {}, sA5 = {}, sA6 = {}, sA7 = {};
    float4 sB0 = {}, sB1 = {}, sB2 = {}, sB3 = {}, sB4 = {}, sB5 = {}, sB6 = {}, sB7 = {};

    for (int kc = 0; kc < 4; ++kc) {
        __syncthreads();
        {   // stage kT chunk: 16 kk x 512 j, transposed. qq = t&3, j = (t>>2)+64*it
            int qq = t & 3;
            int jb = t >> 2;
#pragma unroll
            for (int it = 0; it < 8; ++it) {
                int j = jb + it * 64;
                float4 t4 = *(const float4*)(k + ((size_t)bn * LQ + j) * DKk + kc * 16 + qq * 4);
                kT[(qq * 4 + 0) * 516 + j] = t4.x;
                kT[(qq * 4 + 1) * 516 + j] = t4.y;
                kT[(qq * 4 + 2) * 516 + j] = t4.z;
                kT[(qq * 4 + 3) * 516 + j] = t4.w;
            }
        }
        __syncthreads();
#pragma unroll
        for (int kk = 0; kk < 16; ++kk) {
            float4 a0 = *(const float4*)&qT[(kc * 16 + kk) * 36 + ig * 8];      // broadcast
            float4 a1 = *(const float4*)&qT[(kc * 16 + kk) * 36 + ig * 8 + 4];  // broadcast
            float4 b0 = *(const float4*)&kT[kk * 516 + lane * 4];
            float4 b1 = *(const float4*)&kT[kk * 516 + 256 + lane * 4];
            QK_R(a0.x, sA0, sB0); QK_R(a0.y, sA1, sB1);
            QK_R(a0.z, sA2, sB2); QK_R(a0.w, sA3, sB3);
            QK_R(a1.x, sA4, sB4); QK_R(a1.y, sA5, sB5);
            QK_R(a1.z, sA6, sB6); QK_R(a1.w, sA7, sB7);
        }
    }

    // mask + softmax (width-64, rows fully in-wave) + attn write
    SM_ROW(sA0, sB0, md0[0], md1[0], 0); SM_ROW(sA1, sB1, md0[1], md1[1], 1);
    SM_ROW(sA2, sB2, md0[2], md1[2], 2); SM_ROW(sA3, sB3, md0[3], md1[3], 3);
    SM_ROW(sA4, sB4, md0[4], md1[4], 4); SM_ROW(sA5, sB5, md0[5], md1[5], 5);
    SM_ROW(sA6, sB6, md0[6], md1[6], 6); SM_ROW(sA7, sB7, md0[7], md1[7], 7);

    // ---- PV: thread = jq(wave) x ih8((t>>4)&3) x dh(t&15) ----
    int jq  = t >> 6;            // wave: j-quarter (16 jl) of each 64-chunk
    int ih8 = (t >> 4) & 3;      // rows i0 + ih8*8 .. +7
    int dh  = t & 15;            // d = dh*4 .. +3
    int L15 = lane & 15;
    int slot = ((ig + L15) & 3) * 8;   // owner-write rotated i-slot
    float o[8][4] = {};
#pragma unroll
    for (int c8 = 0; c8 < 8; ++c8) {
        __syncthreads();
        if ((lane >> 4) == (c8 & 3)) {     // owner lanes for this chunk
            if (c8 < 4) {
                PT_WCC(sA0.x, sA1.x, sA2.x, sA3.x, sA4.x, sA5.x, sA6.x, sA7.x, 0);
                PT_WCC(sA0.y, sA1.y, sA2.y, sA3.y, sA4.y, sA5.y, sA6.y, sA7.y, 1);
                PT_WCC(sA0.z, sA1.z, sA2.z, sA3.z, sA4.z, sA5.z, sA6.z, sA7.z, 2);
                PT_WCC(sA0.w, sA1.w, sA2.w, sA3.w, sA4.w, sA5.w, sA6.w, sA7.w, 3);
            } else {
                PT_WCC(sB0.x, sB1.x, sB2.x, sB3.x, sB4.x, sB5.x, sB6.x, sB7.x, 0);
                PT_WCC(sB0.y, sB1.y, sB2.y, sB3.y, sB4.y, sB5.y, sB6.y, sB7.y, 1);
                PT_WCC(sB0.z, sB1.z, sB2.z, sB3.z, sB4.z, sB5.z, sB6.z, sB7.z, 2);
                PT_WCC(sB0.w, sB1.w, sB2.w, sB3.w, sB4.w, sB5.w, sB6.w, sB7.w, 3);
            }
        }
        {   // stage Vs: j = t>>2, dq = (t&3)+4*it (proven layout)
            int vj = t >> 2;
#pragma unroll
            for (int it = 0; it < 4; ++it) {
                int dq = (t & 3) + it * 4;
                *(float4*)&Vs[vj * 68 + dq * 4] =
                    *(const float4*)(v + ((size_t)bn * LQ + c8 * 64 + vj) * DVv + dq * 4);
            }
        }
        __syncthreads();
#pragma unroll 4
        for (int jx = 0; jx < 16; ++jx) {
            int jl = jq * 16 + jx;
            int poff = ((ih8 + (jl >> 2)) & 3) * 8;    // reader rotation = writer's
            float4 pl = *(const float4*)&Pt[jl * 36 + poff];
            float4 ph = *(const float4*)&Pt[jl * 36 + poff + 4];
            float4 v4 = *(const float4*)&Vs[jl * 68 + dh * 4];
            o[0][0] = fmaf(pl.x, v4.x, o[0][0]); o[0][1] = fmaf(pl.x, v4.y, o[0][1]);
            o[0][2] = fmaf(pl.x, v4.z, o[0][2]); o[0][3] = fmaf(pl.x, v4.w, o[0][3]);
            o[1][0] = fmaf(pl.y, v4.x, o[1][0]); o[1][1] = fmaf(pl.y, v4.y, o[1][1]);
            o[1][2] = fmaf(pl.y, v4.z, o[1][2]); o[1][3] = fmaf(pl.y, v4.w, o[1][3]);
            o[2][0] = fmaf(pl.z, v4.x, o[2][0]); o[2][1] = fmaf(pl.z, v4.y, o[2][1]);
            o[2][2] = fmaf(pl.z, v4.z, o[2][2]); o[2][3] = fmaf(pl.z, v4.w, o[2][3]);
            o[3][0] = fmaf(pl.w, v4.x, o[3][0]); o[3][1] = fmaf(pl.w, v4.y, o[3][1]);
            o[3][2] = fmaf(pl.w, v4.z, o[3][2]); o[3][3] = fmaf(pl.w, v4.w, o[3][3]);
            o[4][0] = fmaf(ph.x, v4.x, o[4][0]); o[4][1] = fmaf(ph.x, v4.y, o[4][1]);
            o[4][2] = fmaf(ph.x, v4.z, o[4][2]); o[4][3] = fmaf(ph.x, v4.w, o[4][3]);
            o[5][0] = fmaf(ph.y, v4.x, o[5][0]); o[5][1] = fmaf(ph.y, v4.y, o[5][1]);
            o[5][2] = fmaf(ph.y, v4.z, o[5][2]); o[5][3] = fmaf(ph.y, v4.w, o[5][3]);
            o[6][0] = fmaf(ph.z, v4.x, o[6][0]); o[6][1] = fmaf(ph.z, v4.y, o[6][1]);
            o[6][2] = fmaf(ph.z, v4.z, o[6][2]); o[6][3] = fmaf(ph.z, v4.w, o[6][3]);
            o[7][0] = fmaf(ph.w, v4.x, o[7][0]); o[7][1] = fmaf(ph.w, v4.y, o[7][1]);
            o[7][2] = fmaf(ph.w, v4.z, o[7][2]); o[7][3] = fmaf(ph.w, v4.w, o[7][3]);
        }
    }
    // ---- sequential cross-quarter reduce (single layer, slots*20) ----
    float* red = smem;
    __syncthreads();
    if (jq == 3) {
#pragma unroll
        for (int rr = 0; rr < 8; ++rr)
            *(float4*)&red[((ih8 * 8 + rr) * 16 + dh) * 20] =
                make_float4(o[rr][0], o[rr][1], o[rr][2], o[rr][3]);
    }
    __syncthreads();
    if (jq == 2) {
#pragma unroll
        for (int rr = 0; rr < 8; ++rr) {
            float* p = &red[((ih8 * 8 + rr) * 16 + dh) * 20];
            float4 x = *(const float4*)p;
            *(float4*)p = make_float4(x.x + o[rr][0], x.y + o[rr][1],
                                      x.z + o[rr][2], x.w + o[rr][3]);
        }
    }
    __syncthreads();
    if (jq == 1) {
#pragma unroll
        for (int rr = 0; rr < 8; ++rr) {
            float* p = &red[((ih8 * 8 + rr) * 16 + dh) * 20];
            float4 x = *(const float4*)p;
            *(float4*)p = make_float4(x.x + o[rr][0], x.y + o[rr][1],
                                      x.z + o[rr][2], x.w + o[rr][3]);
        }
    }
    __syncthreads();
    if (jq == 0) {
#pragma unroll
        for (int rr = 0; rr < 8; ++rr) {
            float4 x = *(const float4*)&red[((ih8 * 8 + rr) * 16 + dh) * 20];
            *(float4*)&out[((size_t)bn * LQ + i0 + ih8 * 8 + rr) * DVv + dh * 4] =
                make_float4(x.x + o[rr][0], x.y + o[rr][1],
                            x.z + o[rr][2], x.w + o[rr][3]);
        }
    }
}

// ---------------------------------------------------------------------------
extern "C" void kernel_launch(void* const* d_in, const int* in_sizes, int n_in,
                              void* d_out, int out_size, void* d_ws, size_t ws_size,
                              hipStream_t stream)
{
    const float* q  = (const float*)d_in[0];
    const float* k  = (const float*)d_in[1];
    const float* v  = (const float*)d_in[2];
    const float* d0 = (const float*)d_in[3];
    const float* d1 = (const float*)d_in[4];
    const float* W1 = (const float*)d_in[5];
    const float* b1 = (const float*)d_in[6];
    const float* W2 = (const float*)d_in[7];
    const float* b2 = (const float*)d_in[8];

    float* out  = (float*)d_out;                                  // [2,16,512,64]
    float* attn = out + (size_t)BB * NN * LQ * DVv;               // [2,16,512,512]
    float* dec  = attn + (size_t)BB * NN * LQ * LQ;               // [2,1,512,512]

    // Scratch inside the attn region (32 MB); fully consumed before
    // fused_attn overwrites every attn element (same stream => ordered).
    char* scratch = (char*)attn;
    double* U64 = (double*)(scratch);                             // 0..2 MB
    double* W64 = (double*)(scratch + (2u << 20));                // 2..4 MB
    float*  U32 = (float*) (scratch + (4u << 20));                // 4..5 MB
    float*  W32 = (float*) (scratch + (5u << 20));                // 5..6 MB

    mlp_stage1<<<1024, 256, 0, stream>>>(d0, d1, W1, b1, U64, W64, U32, W32);
    dec_full<<<512, 256, 0, stream>>>(U32, W32, U64, W64, W2, b2, dec);
    fused_attn<<<512, 256, 0, stream>>>(q, k, v, dec, attn, out);
}

// Round 16
// 156.584 us; speedup vs baseline: 1.0191x; 1.0191x over previous
//
#include <hip/hip_runtime.h>

#define BB 2
#define NN 16
#define LQ 512
#define DKk 64
#define DVv 64
#define DDd 128
#define H2 256
#define NEG_INF -1e9f

// ---------------------------------------------------------------------------
// Stage 1 v2 (proven): 2 rows per block, grid 1024, 4 blocks/CU.
// Per-(row,g) fp64 chain unchanged -> bit-identical U/W outputs.
// ---------------------------------------------------------------------------
__global__ __launch_bounds__(256) void mlp_stage1(
    const float* __restrict__ d0, const float* __restrict__ d1,
    const float* __restrict__ W1, const float* __restrict__ b1,
    double* __restrict__ U64, double* __restrict__ W64,
    float* __restrict__ U32, float* __restrict__ W32)
{
    __shared__ float drow[2][DDd];
    int gid = blockIdx.x;            // half(2) x rowgroup(512)
    int half = gid >> 9;
    int r0 = (gid & 511) * 2;        // rows r0..r0+1 of 1024
    const float* din = half ? d1 : d0;
    int w1off = half ? DDd : 0;
    double* o64 = half ? W64 : U64;
    float* o32 = half ? W32 : U32;
    int t = threadIdx.x;
    drow[t >> 7][t & 127] = din[(size_t)(r0 + (t >> 7)) * DDd + (t & 127)];
    __syncthreads();
    int g = t;
    double acc[2] = {};
#pragma unroll 2
    for (int f = 0; f < DDd; f += 4) {
        double w0 = (double)W1[(w1off + f + 0) * H2 + g];
        double w1 = (double)W1[(w1off + f + 1) * H2 + g];
        double w2 = (double)W1[(w1off + f + 2) * H2 + g];
        double w3 = (double)W1[(w1off + f + 3) * H2 + g];
#pragma unroll
        for (int r = 0; r < 2; ++r) {
            float4 dr = *(const float4*)&drow[r][f];
            acc[r] = fma((double)dr.x, w0, acc[r]);
            acc[r] = fma((double)dr.y, w1, acc[r]);
            acc[r] = fma((double)dr.z, w2, acc[r]);
            acc[r] = fma((double)dr.w, w3, acc[r]);
        }
    }
    double bb = half ? 0.0 : (double)b1[g];
#pragma unroll
    for (int r = 0; r < 2; ++r) {
        double a = acc[r] + bb;
        o64[(size_t)(r0 + r) * H2 + g] = a;
        o32[(size_t)(r0 + r) * H2 + g] = (float)a;
    }
}

// ---------------------------------------------------------------------------
// dec_full v8 (kept): 2i x 2j thread tile, g-major LDS, single staging pass;
// in-block fp64 re-eval of |gap|<2e-2 band -> bit-identical decisions.
// ---------------------------------------------------------------------------
__global__ __launch_bounds__(256, 2) void dec_full(
    const float* __restrict__ U32, const float* __restrict__ W32,
    const double* __restrict__ U64, const double* __restrict__ W64,
    const float* __restrict__ W2, const float* __restrict__ b2,
    float* __restrict__ dec_out)
{
    __shared__ __align__(16) float Ut[H2][36];    // [g][i]  36 KB
    __shared__ __align__(16) float Wt[H2][36];    // [g][j]  36 KB
    __shared__ float gvs[H2];
    __shared__ int lbuf[1024];
    __shared__ int lcnt;
    int bid = blockIdx.x;            // b(2) x it(16) x jt(16)
    int b  = bid >> 8;
    int i0 = ((bid >> 4) & 15) * 32;
    int j0 = (bid & 15) * 32;
    int t = threadIdx.x;
    gvs[t] = W2[t * 2 + 1] - W2[t * 2];
    if (t == 0) lcnt = 0;
    float bias = b2[1] - b2[0];
    {   // stage U,W transposed: row = t>>3 (0..31), gq = t&7; 8 f4 each
        int r = t >> 3, gq = t & 7;
        const float* su = U32 + ((size_t)(b * LQ) + i0 + r) * H2;
        const float* sw = W32 + ((size_t)(b * LQ) + j0 + r) * H2;
#pragma unroll
        for (int s = 0; s < 8; ++s) {
            int g = gq * 4 + s * 32;
            float4 u4 = *(const float4*)(su + g);
            Ut[g + 0][r] = u4.x; Ut[g + 1][r] = u4.y;
            Ut[g + 2][r] = u4.z; Ut[g + 3][r] = u4.w;
            float4 w4 = *(const float4*)(sw + g);
            Wt[g + 0][r] = w4.x; Wt[g + 1][r] = w4.y;
            Wt[g + 2][r] = w4.z; Wt[g + 3][r] = w4.w;
        }
    }
    __syncthreads();
    int pi = t >> 4, pj = t & 15;    // i = i0+pi*2+{0,1}; j = j0+pj*2+{0,1}
    float a00 = 0.f, a01 = 0.f, a10 = 0.f, a11 = 0.f;
#pragma unroll 8
    for (int g = 0; g < H2; ++g) {
        float2 u2 = *(const float2*)&Ut[g][pi * 2];
        float2 w2 = *(const float2*)&Wt[g][pj * 2];
        float gv = gvs[g];
        a00 = fmaf(fmaxf(u2.x + w2.x, 0.f), gv, a00);
        a01 = fmaf(fmaxf(u2.x + w2.y, 0.f), gv, a01);
        a10 = fmaf(fmaxf(u2.y + w2.x, 0.f), gv, a10);
        a11 = fmaf(fmaxf(u2.y + w2.y, 0.f), gv, a11);
    }
    int row0 = b * LQ + i0 + pi * 2;
    float g00 = a00 + bias, g01 = a01 + bias;
    float g10 = a10 + bias, g11 = a11 + bias;
    int jb = j0 + pj * 2;
    *(float2*)&dec_out[(size_t)row0 * LQ + jb] =
        make_float2(g00 > 0.f ? 1.f : 0.f, g01 > 0.f ? 1.f : 0.f);
    *(float2*)&dec_out[(size_t)(row0 + 1) * LQ + jb] =
        make_float2(g10 > 0.f ? 1.f : 0.f, g11 > 0.f ? 1.f : 0.f);
    if (fabsf(g00) < 2e-2f) { int lx = atomicAdd(&lcnt, 1); lbuf[lx] = (row0 << 9) | jb; }
    if (fabsf(g01) < 2e-2f) { int lx = atomicAdd(&lcnt, 1); lbuf[lx] = (row0 << 9) | (jb + 1); }
    if (fabsf(g10) < 2e-2f) { int lx = atomicAdd(&lcnt, 1); lbuf[lx] = ((row0 + 1) << 9) | jb; }
    if (fabsf(g11) < 2e-2f) { int lx = atomicAdd(&lcnt, 1); lbuf[lx] = ((row0 + 1) << 9) | (jb + 1); }
    __syncthreads();
    // ---- in-block fp64 re-eval (gap64's exact math/order), wave per pair ----
    int nloc = lcnt;
    int wv = t >> 6, ln = t & 63;
    for (int x = wv; x < nloc; x += 4) {
        int pij = lbuf[x];
        int j = pij & (LQ - 1);
        int prow = pij >> 9;
        int pb = prow >> 9;
        const double* u = U64 + (size_t)prow * H2;
        const double* w = W64 + ((size_t)(pb * LQ) + j) * H2;
        double acc = 0.0;
        for (int g = ln; g < H2; g += 64) {
            double tv = u[g] + w[g];
            tv = tv > 0.0 ? tv : 0.0;
            acc = fma(tv, (double)W2[g * 2 + 1] - (double)W2[g * 2 + 0], acc);
        }
#pragma unroll
        for (int off = 32; off; off >>= 1) acc += __shfl_xor(acc, off, 64);
        if (ln == 0) {
            acc += (double)b2[1] - (double)b2[0];
            dec_out[(size_t)prow * LQ + j] = acc > 0.0 ? 1.f : 0.f;
        }
    }
}

// ---------------------------------------------------------------------------
// Fused attention v10: QK/softmax byte-identical to R14 v8 (T14 prefetch
// reverted — R15 A/B showed it null, +32 VGPR). PV chunk 64 -> 128 j:
// barriers 28 -> 20 (at 2 blocks/CU each block-wide barrier is poorly
// covered). All 256 threads stage Pt every chunk (no owner predicate).
// Pt[128][36], rotation quad (tiq + (jl>>2))&7: writer instr spreads its
// 64 writes over all 8 bank-quads exactly uniformly (tjq 0..7 ->
// {0,5,2,7,4,1,6,3}); reads wave-uniform-row, 4-addr multicast. Vs[128][68]
// proven stride. smem 53.2 KB (2 blocks/CU retained; grid-capped anyway).
// ---------------------------------------------------------------------------
#define QK_R(ar, sa, sb)                                   \
    sa.x = fmaf(ar, b0.x, sa.x); sa.y = fmaf(ar, b0.y, sa.y); \
    sa.z = fmaf(ar, b0.z, sa.z); sa.w = fmaf(ar, b0.w, sa.w); \
    sb.x = fmaf(ar, b1.x, sb.x); sb.y = fmaf(ar, b1.y, sb.y); \
    sb.z = fmaf(ar, b1.z, sb.z); sb.w = fmaf(ar, b1.w, sb.w);

__global__ __launch_bounds__(256) void fused_attn(
    const float* __restrict__ q, const float* __restrict__ k,
    const float* __restrict__ v, const float* __restrict__ dec,
    float* __restrict__ attn, float* __restrict__ out)
{
    __shared__ __align__(16) float smem[13312];   // 53.2 KB, phase-overlaid
    float* qT = smem;            // [64][36]    (QK)
    float* kT = smem + 2304;     // [64][132]   (QK)
    float* Pt = smem;            // [128][36]   (PV, rotated quads)
    float* Vs = smem + 4608;     // [128][68]   (PV)
    int bid = blockIdx.x;
    int bn = bid >> 4;
    int i0 = (bid & 15) * 32;
    int b = bn >> 4;
    int t = threadIdx.x;

    {   // stage qT (transpose): i = t>>3, kkq = (t&7)+8*it
        int qi = t >> 3;
        const float* src = q + ((size_t)bn * LQ + i0 + qi) * DKk;
#pragma unroll
        for (int it = 0; it < 2; ++it) {
            int kkq = (t & 7) + it * 8;
            float4 t4 = *(const float4*)(src + kkq * 4);
            qT[(kkq * 4 + 0) * 36 + qi] = t4.x;
            qT[(kkq * 4 + 1) * 36 + qi] = t4.y;
            qT[(kkq * 4 + 2) * 36 + qi] = t4.z;
            qT[(kkq * 4 + 3) * 36 + qi] = t4.w;
        }
    }
    int tiq = t >> 5;            // 0..7  -> i = tiq*4 + r
    int tjq = t & 31;            // 0..31 -> j = c*128 + tjq*4 + cc
    float s[4][4][4];

#pragma unroll
    for (int c = 0; c < 4; ++c) {
        __syncthreads();
        {   // stage kT (transpose): j = (t>>2)+(it&1)*64, kkq = (t&3)+(it>>1)*4
            int kj = t >> 2;
#pragma unroll
            for (int it = 0; it < 8; ++it) {
                int jj = kj + (it & 1) * 64;
                int kkq = (t & 3) + (it >> 1) * 4;
                float4 t4 = *(const float4*)(k + ((size_t)bn * LQ + c * 128 + jj) * DKk + kkq * 4);
                kT[(kkq * 4 + 0) * 132 + jj] = t4.x;
                kT[(kkq * 4 + 1) * 132 + jj] = t4.y;
                kT[(kkq * 4 + 2) * 132 + jj] = t4.z;
                kT[(kkq * 4 + 3) * 132 + jj] = t4.w;
            }
        }
        __syncthreads();
        float acc[4][4] = {};
#pragma unroll 8
        for (int kk = 0; kk < 64; ++kk) {
            float4 a  = *(const float4*)&qT[kk * 36 + tiq * 4];
            float4 bb = *(const float4*)&kT[kk * 132 + tjq * 4];
            acc[0][0] = fmaf(a.x, bb.x, acc[0][0]); acc[0][1] = fmaf(a.x, bb.y, acc[0][1]);
            acc[0][2] = fmaf(a.x, bb.z, acc[0][2]); acc[0][3] = fmaf(a.x, bb.w, acc[0][3]);
            acc[1][0] = fmaf(a.y, bb.x, acc[1][0]); acc[1][1] = fmaf(a.y, bb.y, acc[1][1]);
            acc[1][2] = fmaf(a.y, bb.z, acc[1][2]); acc[1][3] = fmaf(a.y, bb.w, acc[1][3]);
            acc[2][0] = fmaf(a.z, bb.x, acc[2][0]); acc[2][1] = fmaf(a.z, bb.y, acc[2][1]);
            acc[2][2] = fmaf(a.z, bb.z, acc[2][2]); acc[2][3] = fmaf(a.z, bb.w, acc[2][3]);
            acc[3][0] = fmaf(a.w, bb.x, acc[3][0]); acc[3][1] = fmaf(a.w, bb.y, acc[3][1]);
            acc[3][2] = fmaf(a.w, bb.z, acc[3][2]); acc[3][3] = fmaf(a.w, bb.w, acc[3][3]);
        }
#pragma unroll
        for (int r = 0; r < 4; ++r) {
            float4 m4 = *(const float4*)&dec[((size_t)(b * LQ) + i0 + tiq * 4 + r) * LQ + c * 128 + tjq * 4];
            s[c][r][0] = m4.x != 0.f ? acc[r][0] * 0.125f : NEG_INF;
            s[c][r][1] = m4.y != 0.f ? acc[r][1] * 0.125f : NEG_INF;
            s[c][r][2] = m4.z != 0.f ? acc[r][2] * 0.125f : NEG_INF;
            s[c][r][3] = m4.w != 0.f ? acc[r][3] * 0.125f : NEG_INF;
        }
    }
    // softmax over 512 j per row (width-32 shuffle groups = tjq)
#pragma unroll
    for (int r = 0; r < 4; ++r) {
        float m = NEG_INF;
#pragma unroll
        for (int c = 0; c < 4; ++c)
#pragma unroll
            for (int cc = 0; cc < 4; ++cc) m = fmaxf(m, s[c][r][cc]);
#pragma unroll
        for (int off = 1; off < 32; off <<= 1) m = fmaxf(m, __shfl_xor(m, off, 32));
        float sum = 0.f;
#pragma unroll
        for (int c = 0; c < 4; ++c)
#pragma unroll
            for (int cc = 0; cc < 4; ++cc) {
                float e = __expf(s[c][r][cc] - m);
                s[c][r][cc] = e; sum += e;
            }
#pragma unroll
        for (int off = 1; off < 32; off <<= 1) sum += __shfl_xor(sum, off, 32);
        float inv = 1.f / sum;
#pragma unroll
        for (int c = 0; c < 4; ++c)
#pragma unroll
            for (int cc = 0; cc < 4; ++cc) s[c][r][cc] *= inv;
    }
#pragma unroll
    for (int c = 0; c < 4; ++c)
#pragma unroll
        for (int r = 0; r < 4; ++r) {
            float4 wv = make_float4(s[c][r][0], s[c][r][1], s[c][r][2], s[c][r][3]);
            *(float4*)&attn[((size_t)bn * LQ + i0 + tiq * 4 + r) * LQ + c * 128 + tjq * 4] = wv;
        }

    // ---- PV v10: four 128-j chunks; thread = jq(wave) x ih8 x dh ----
    int jq  = t >> 6;            // wave: 32 jl of each 128-chunk
    int ih8 = (t >> 4) & 3;      // rows i0 + ih8*8 .. +7
    int dh  = t & 15;            // d = dh*4 .. +3
    int wslot = ((tiq + (tjq & 7)) & 7) * 4;   // writer rotation (jl>>2 = tjq)
    float o[8][4] = {};
#pragma unroll
    for (int c = 0; c < 4; ++c) {
        __syncthreads();
        {   // stage Pt: every thread writes its 4 j-rows of chunk c
#pragma unroll
            for (int cc = 0; cc < 4; ++cc) {
                int jl = tjq * 4 + cc;
                *(float4*)&Pt[jl * 36 + wslot] =
                    make_float4(s[c][0][cc], s[c][1][cc], s[c][2][cc], s[c][3][cc]);
            }
        }
        {   // stage Vs: 128 rows; vj = t>>1, f4 = (t&1)+2*it
            int vj = t >> 1;
#pragma unroll
            for (int it = 0; it < 8; ++it) {
                int f4 = (t & 1) + it * 2;
                *(float4*)&Vs[vj * 68 + f4 * 4] =
                    *(const float4*)(v + ((size_t)bn * LQ + c * 128 + vj) * DVv + f4 * 4);
            }
        }
        __syncthreads();
#pragma unroll 4
        for (int jx = 0; jx < 32; ++jx) {
            int jl = jq * 32 + jx;
            int rr7 = (jl >> 2) & 7;
            float4 pl = *(const float4*)&Pt[jl * 36 + ((ih8 * 2 + rr7) & 7) * 4];
            float4 ph = *(const float4*)&Pt[jl * 36 + ((ih8 * 2 + 1 + rr7) & 7) * 4];
            float4 v4 = *(const float4*)&Vs[jl * 68 + dh * 4];
            o[0][0] = fmaf(pl.x, v4.x, o[0][0]); o[0][1] = fmaf(pl.x, v4.y, o[0][1]);
            o[0][2] = fmaf(pl.x, v4.z, o[0][2]); o[0][3] = fmaf(pl.x, v4.w, o[0][3]);
            o[1][0] = fmaf(pl.y, v4.x, o[1][0]); o[1][1] = fmaf(pl.y, v4.y, o[1][1]);
            o[1][2] = fmaf(pl.y, v4.z, o[1][2]); o[1][3] = fmaf(pl.y, v4.w, o[1][3]);
            o[2][0] = fmaf(pl.z, v4.x, o[2][0]); o[2][1] = fmaf(pl.z, v4.y, o[2][1]);
            o[2][2] = fmaf(pl.z, v4.z, o[2][2]); o[2][3] = fmaf(pl.z, v4.w, o[2][3]);
            o[3][0] = fmaf(pl.w, v4.x, o[3][0]); o[3][1] = fmaf(pl.w, v4.y, o[3][1]);
            o[3][2] = fmaf(pl.w, v4.z, o[3][2]); o[3][3] = fmaf(pl.w, v4.w, o[3][3]);
            o[4][0] = fmaf(ph.x, v4.x, o[4][0]); o[4][1] = fmaf(ph.x, v4.y, o[4][1]);
            o[4][2] = fmaf(ph.x, v4.z, o[4][2]); o[4][3] = fmaf(ph.x, v4.w, o[4][3]);
            o[5][0] = fmaf(ph.y, v4.x, o[5][0]); o[5][1] = fmaf(ph.y, v4.y, o[5][1]);
            o[5][2] = fmaf(ph.y, v4.z, o[5][2]); o[5][3] = fmaf(ph.y, v4.w, o[5][3]);
            o[6][0] = fmaf(ph.z, v4.x, o[6][0]); o[6][1] = fmaf(ph.z, v4.y, o[6][1]);
            o[6][2] = fmaf(ph.z, v4.z, o[6][2]); o[6][3] = fmaf(ph.z, v4.w, o[6][3]);
            o[7][0] = fmaf(ph.w, v4.x, o[7][0]); o[7][1] = fmaf(ph.w, v4.y, o[7][1]);
            o[7][2] = fmaf(ph.w, v4.z, o[7][2]); o[7][3] = fmaf(ph.w, v4.w, o[7][3]);
        }
    }
    // ---- sequential cross-quarter reduce (single layer, slots*20) ----
    float* red = smem;
    __syncthreads();
    if (jq == 3) {
#pragma unroll
        for (int rr = 0; rr < 8; ++rr)
            *(float4*)&red[((ih8 * 8 + rr) * 16 + dh) * 20] =
                make_float4(o[rr][0], o[rr][1], o[rr][2], o[rr][3]);
    }
    __syncthreads();
    if (jq == 2) {
#pragma unroll
        for (int rr = 0; rr < 8; ++rr) {
            float* p = &red[((ih8 * 8 + rr) * 16 + dh) * 20];
            float4 x = *(const float4*)p;
            *(float4*)p = make_float4(x.x + o[rr][0], x.y + o[rr][1],
                                      x.z + o[rr][2], x.w + o[rr][3]);
        }
    }
    __syncthreads();
    if (jq == 1) {
#pragma unroll
        for (int rr = 0; rr < 8; ++rr) {
            float* p = &red[((ih8 * 8 + rr) * 16 + dh) * 20];
            float4 x = *(const float4*)p;
            *(float4*)p = make_float4(x.x + o[rr][0], x.y + o[rr][1],
                                      x.z + o[rr][2], x.w + o[rr][3]);
        }
    }
    __syncthreads();
    if (jq == 0) {
#pragma unroll
        for (int rr = 0; rr < 8; ++rr) {
            float4 x = *(const float4*)&red[((ih8 * 8 + rr) * 16 + dh) * 20];
            *(float4*)&out[((size_t)bn * LQ + i0 + ih8 * 8 + rr) * DVv + dh * 4] =
                make_float4(x.x + o[rr][0], x.y + o[rr][1],
                            x.z + o[rr][2], x.w + o[rr][3]);
        }
    }
}

// ---------------------------------------------------------------------------
extern "C" void kernel_launch(void* const* d_in, const int* in_sizes, int n_in,
                              void* d_out, int out_size, void* d_ws, size_t ws_size,
                              hipStream_t stream)
{
    const float* q  = (const float*)d_in[0];
    const float* k  = (const float*)d_in[1];
    const float* v  = (const float*)d_in[2];
    const float* d0 = (const float*)d_in[3];
    const float* d1 = (const float*)d_in[4];
    const float* W1 = (const float*)d_in[5];
    const float* b1 = (const float*)d_in[6];
    const float* W2 = (const float*)d_in[7];
    const float* b2 = (const float*)d_in[8];

    float* out  = (float*)d_out;                                  // [2,16,512,64]
    float* attn = out + (size_t)BB * NN * LQ * DVv;               // [2,16,512,512]
    float* dec  = attn + (size_t)BB * NN * LQ * LQ;               // [2,1,512,512]

    // Scratch inside the attn region (32 MB); fully consumed before
    // fused_attn overwrites every attn element (same stream => ordered).
    char* scratch = (char*)attn;
    double* U64 = (double*)(scratch);                             // 0..2 MB
    double* W64 = (double*)(scratch + (2u << 20));                // 2..4 MB
    float*  U32 = (float*) (scratch + (4u << 20));                // 4..5 MB
    float*  W32 = (float*) (scratch + (5u << 20));                // 5..6 MB

    mlp_stage1<<<1024, 256, 0, stream>>>(d0, d1, W1, b1, U64, W64, U32, W32);
    dec_full<<<512, 256, 0, stream>>>(U32, W32, U64, W64, W2, b2, dec);
    fused_attn<<<512, 256, 0, stream>>>(q, k, v, dec, attn, out);
}